// Round 6
// baseline (1903.072 us; speedup 1.0000x reference)
//
#include <hip/hip_runtime.h>
#include <hip/hip_bf16.h>

// ---- problem constants (fixed by setup_inputs) ----
#define NN   32768
#define EE   262144
#define SS   128
#define NF_  90
#define NC_  36
#define OD_  64
#define D0_  190
#define DX_  380
#define GIN_ 256
#define GH_  512

typedef __attribute__((ext_vector_type(8))) short  s8v;   // 8 bf16 = 4 VGPRs
typedef __attribute__((ext_vector_type(4))) float  f4v;   // 4 fp32

typedef const __attribute__((address_space(1))) void* gas_ptr;
typedef __attribute__((address_space(3))) void*       las_ptr;

// ---- bf16 helpers (manual, RN) ----
__device__ __forceinline__ float bf2f(unsigned short u) {
  return __uint_as_float(((unsigned)u) << 16);
}
__device__ __forceinline__ unsigned short f2bf(float f) {
  unsigned u = __float_as_uint(f);
  u += 0x7FFFu + ((u >> 16) & 1u);
  return (unsigned short)(u >> 16);
}

// ---------------------------------------------------------------------------
// device-wide barrier. SAFE ONLY because every kernel using it declares
// __launch_bounds__(256,4) -> <=128 VGPR -> 4 blocks/CU -> 1024-block
// co-residency; all grids are <= 1024 blocks. Release/acquire threadfences
// emit the cross-XCD L2 writeback/invalidate on gfx950.
// ---------------------------------------------------------------------------
__device__ __forceinline__ void grid_bar(int* bar, int nb) {
  __syncthreads();
  if (threadIdx.x == 0) {
    __threadfence();   // release: make prior writes visible device-wide
    __hip_atomic_fetch_add(bar, 1, __ATOMIC_RELEASE, __HIP_MEMORY_SCOPE_AGENT);
    while (__hip_atomic_load(bar, __ATOMIC_RELAXED, __HIP_MEMORY_SCOPE_AGENT) < nb) {
      __builtin_amdgcn_s_sleep(2);
    }
  }
  __syncthreads();
  __threadfence();     // acquire: invalidate stale caches before reading
}

// ---------------------------------------------------------------------------
// degree / CSR build (parallel 3-phase scan)
// ---------------------------------------------------------------------------
__global__ void deg_count(const int* __restrict__ dst, int* __restrict__ deg) {
  int e = blockIdx.x * 256 + threadIdx.x;
  if (e < EE) atomicAdd(&deg[dst[e]], 1);
}

__global__ __launch_bounds__(256) void blk_sum_k(const int* __restrict__ deg,
                                                 int* __restrict__ bsum) {
  __shared__ int buf[256];
  int tid = threadIdx.x;
  buf[tid] = deg[blockIdx.x * 256 + tid];
  __syncthreads();
  for (int off = 128; off > 0; off >>= 1) {
    if (tid < off) buf[tid] += buf[tid + off];
    __syncthreads();
  }
  if (tid == 0) bsum[blockIdx.x] = buf[0];
}

__global__ __launch_bounds__(128) void blk_scan_k(const int* __restrict__ bsum,
                                                  int* __restrict__ boff) {
  __shared__ int buf[128];
  int tid = threadIdx.x;
  int v = bsum[tid];
  buf[tid] = v;
  __syncthreads();
  for (int d = 1; d < 128; d <<= 1) {
    int t = (tid >= d) ? buf[tid - d] : 0;
    __syncthreads();
    if (tid >= d) buf[tid] += t;
    __syncthreads();
  }
  boff[tid] = buf[tid] - v;   // exclusive
}

__global__ __launch_bounds__(256) void offsets_k(const int* __restrict__ deg,
                                                 const int* __restrict__ boff,
                                                 int* __restrict__ offsets,
                                                 float* __restrict__ inv_deg) {
  __shared__ int buf[256];
  int tid = threadIdx.x;
  int i = blockIdx.x * 256 + tid;
  int v = deg[i];
  buf[tid] = v;
  __syncthreads();
  for (int d = 1; d < 256; d <<= 1) {
    int t = (tid >= d) ? buf[tid - d] : 0;
    __syncthreads();
    if (tid >= d) buf[tid] += t;
    __syncthreads();
  }
  offsets[i] = boff[blockIdx.x] + buf[tid] - v;
  inv_deg[i] = 1.0f / fmaxf((float)v, 1.0f);
  if (i == 0) offsets[NN] = EE;
}

__global__ void bucket_k(const int* __restrict__ src, const int* __restrict__ dst,
                         const int* __restrict__ offsets, int* __restrict__ cursor,
                         int* __restrict__ srcs) {
  int e = blockIdx.x * 256 + threadIdx.x;
  if (e < EE) {
    int d = dst[e];
    int pos = offsets[d] + atomicAdd(&cursor[d], 1);
    srcs[pos] = src[e];
  }
}

// ---------------------------------------------------------------------------
// shared GEMM core: acc = A1*B1^T (+ A2*B2^T), 128x128 tile, mfma 16x16x32,
// async global_load_lds staging, LDS layout [koff(4)][row(128)][8 bf16]
// ---------------------------------------------------------------------------
__device__ __forceinline__ void stage_tile_async(const unsigned short* __restrict__ G, int ld,
                                                 int base_row, int k0,
                                                 unsigned short* __restrict__ lds, int tid) {
#pragma unroll
  for (int i = 0; i < 2; ++i) {
    int c = tid + i * 256;        // 0..511
    int row = c & 127;
    int off = c >> 7;             // 0..3 (k chunk of 8 bf16)
    const unsigned short* src = G + (size_t)(base_row + row) * ld + k0 + off * 8;
    unsigned short* dst = lds + off * 1024 + row * 8;
    __builtin_amdgcn_global_load_lds((gas_ptr)(const void*)src, (las_ptr)(void*)dst,
                                     16, 0, 0);
  }
}

__device__ __forceinline__ void gemm_core(
    const unsigned short* __restrict__ A1, int lda1,
    const unsigned short* __restrict__ B1, int ldb1, int K1,
    const unsigned short* __restrict__ A2, int lda2,
    const unsigned short* __restrict__ B2, int ldb2, int K2,
    int bm, int bn, int tid,
    unsigned short* As, unsigned short* Bs, f4v (&acc)[4][4])
{
  int lane = tid & 63;
  int w = tid >> 6;
  int wm = (w & 1) * 64;
  int wn = (w >> 1) * 64;
  int quad = lane >> 4;
  int r16 = lane & 15;
#pragma unroll 1
  for (int ph = 0; ph < 2; ++ph) {
    const unsigned short* A = ph ? A2 : A1;
    const unsigned short* B = ph ? B2 : B1;
    int lda = ph ? lda2 : lda1;
    int ldb = ph ? ldb2 : ldb1;
    int K = ph ? K2 : K1;
    for (int k0 = 0; k0 < K; k0 += 32) {
      stage_tile_async(A, lda, bm, k0, As, tid);
      stage_tile_async(B, ldb, bn, k0, Bs, tid);
      __syncthreads();
      s8v af[4], bfr[4];
#pragma unroll
      for (int mi = 0; mi < 4; ++mi)
        af[mi] = *(const s8v*)&As[quad * 1024 + (wm + mi * 16 + r16) * 8];
#pragma unroll
      for (int ni = 0; ni < 4; ++ni)
        bfr[ni] = *(const s8v*)&Bs[quad * 1024 + (wn + ni * 16 + r16) * 8];
#pragma unroll
      for (int mi = 0; mi < 4; ++mi)
#pragma unroll
        for (int ni = 0; ni < 4; ++ni)
          acc[mi][ni] = __builtin_amdgcn_mfma_f32_16x16x32_bf16(
              af[mi], bfr[ni], acc[mi][ni], 0, 0, 0);
      __syncthreads();
    }
  }
}

// ---- weight conversion chunk boundaries ----
#define CW1  73728        // w1b  [384x192]
#define CW2  172032       // w2b  [256x384]
#define CWL1 303104       // wl1b [512x256]
#define CWR1 434176
#define CWL2 696320       // [512x512]
#define CWR2 958464
#define CWL3 1220608
#define CWR3 1482752

// ---------------------------------------------------------------------------
// k_mlp1: phaseA {zero stats, init out, convert weights, build x0} | bar |
//         GEMM(x0@w1^T)+leaky+GLN-stats | bar | GLN apply -> BF2 (bf16,384)
// grid 768 = 3 n-tiles x 256 m-tiles
// ---------------------------------------------------------------------------
__global__ __launch_bounds__(256, 4) void k_mlp1(
    const float* __restrict__ nf, const float* __restrict__ ncf,
    const float* __restrict__ emb, const int* __restrict__ ops,
    const float* __restrict__ w1, const float* __restrict__ w2,
    const float* __restrict__ wl1, const float* __restrict__ wr1,
    const float* __restrict__ wl2, const float* __restrict__ wr2,
    const float* __restrict__ wl3, const float* __restrict__ wr3,
    unsigned short* __restrict__ w1b, unsigned short* __restrict__ w2b,
    unsigned short* __restrict__ wl1b, unsigned short* __restrict__ wr1b,
    unsigned short* __restrict__ wl2b, unsigned short* __restrict__ wr2b,
    unsigned short* __restrict__ wl3b, unsigned short* __restrict__ wr3b,
    unsigned short* __restrict__ x0,          // BF1
    const float* __restrict__ b1, const float* __restrict__ g1,
    const float* __restrict__ be1,
    unsigned short* __restrict__ outbf,       // BF2 [NN,384]
    float* __restrict__ stat_all, float* __restrict__ outp,
    const float* __restrict__ bc, int* bar0, int* bar1)
{
  __shared__ unsigned short As[4096];
  __shared__ unsigned short Bs[4096];
  __shared__ float red[256];
  int tid = threadIdx.x;
  int L = blockIdx.x;
  const int T = 768 * 256;
  int gidx = L * 256 + tid;

  // ---- phase A ----
  for (int i = gidx; i < 2560; i += T) stat_all[i] = 0.0f;
  if (gidx < SS) outp[gidx] = bc[0];
  for (int i = gidx; i < CWR3; i += T) {
    if (i < CW1) {
      int r = i / 192, c = i - r * 192;
      w1b[i] = f2bf((r < DX_ && c < D0_) ? w1[r * D0_ + c] : 0.0f);
    } else if (i < CW2) {
      int j = i - CW1;
      int r = j / 384, c = j - r * 384;
      w2b[j] = f2bf((c < DX_) ? w2[r * DX_ + c] : 0.0f);
    } else if (i < CWL1) { int j = i - CW2;  wl1b[j] = f2bf(wl1[j]); }
    else if (i < CWR1)   { int j = i - CWL1; wr1b[j] = f2bf(wr1[j]); }
    else if (i < CWL2)   { int j = i - CWR1; wl2b[j] = f2bf(wl2[j]); }
    else if (i < CWR2)   { int j = i - CWL2; wr2b[j] = f2bf(wr2[j]); }
    else if (i < CWL3)   { int j = i - CWR2; wl3b[j] = f2bf(wl3[j]); }
    else                 { int j = i - CWL3; wr3b[j] = f2bf(wr3[j]); }
  }
  for (int i = gidx; i < NN * 192; i += T) {
    int n = i / 192;
    int c = i - n * 192;
    float v;
    if (c < NF_)            v = nf[n * NF_ + c];
    else if (c < NF_ + NC_) v = ncf[n * NC_ + (c - NF_)];
    else if (c < D0_)       v = emb[ops[n] * OD_ + (c - (NF_ + NC_))];
    else                    v = 0.0f;
    x0[i] = f2bf(v);
  }
  grid_bar(bar0, 768);

  // ---- GEMM ----
  int bn = (L % 3) * 128;
  int bm = (L / 3) * 128;
  int lane = tid & 63;
  int w = tid >> 6;
  int wm = (w & 1) * 64, wn = (w >> 1) * 64;
  int quad = lane >> 4, r16 = lane & 15;
  f4v acc[4][4] = {};
  gemm_core(x0, 192, w1b, 192, 192, nullptr, 0, nullptr, 0, 0,
            bm, bn, tid, As, Bs, acc);

  // leaky(acc+bias) back into acc, GLN scalar stats
  int seg = bm >> 8;
  float lsum = 0.0f, lssq = 0.0f;
#pragma unroll
  for (int mi = 0; mi < 4; ++mi) {
#pragma unroll
    for (int ni = 0; ni < 4; ++ni) {
      int gn = bn + wn + ni * 16 + r16;
      if (gn < DX_) {
        float bv = b1[gn];
#pragma unroll
        for (int r = 0; r < 4; ++r) {
          float v = acc[mi][ni][r] + bv;
          v = (v >= 0.0f) ? v : 0.01f * v;
          acc[mi][ni][r] = v;
          lsum += v;
          lssq += v * v;
        }
      }
    }
  }
  red[tid] = lsum;
  __syncthreads();
  for (int off = 128; off > 0; off >>= 1) {
    if (tid < off) red[tid] += red[tid + off];
    __syncthreads();
  }
  if (tid == 0) atomicAdd(&stat_all[seg], red[0]);
  __syncthreads();
  red[tid] = lssq;
  __syncthreads();
  for (int off = 128; off > 0; off >>= 1) {
    if (tid < off) red[tid] += red[tid + off];
    __syncthreads();
  }
  if (tid == 0) atomicAdd(&stat_all[128 + seg], red[0]);

  grid_bar(bar1, 768);

  // ---- GLN apply from registers -> bf16 [NN,384] ----
  float cnt = 256.0f * (float)DX_;
  float m = stat_all[seg] / cnt;
  float var = stat_all[128 + seg] / cnt - m * m;
  float inv = rsqrtf(var + 1e-5f);
#pragma unroll
  for (int mi = 0; mi < 4; ++mi) {
    int gm = bm + wm + mi * 16 + quad * 4;
#pragma unroll
    for (int ni = 0; ni < 4; ++ni) {
      int gn = bn + wn + ni * 16 + r16;
      float gg = (gn < DX_) ? g1[gn] : 0.0f;
      float bb = (gn < DX_) ? be1[gn] : 0.0f;
#pragma unroll
      for (int r = 0; r < 4; ++r) {
        float vv = (gn < DX_) ? ((acc[mi][ni][r] - m) * inv * gg + bb) : 0.0f;
        outbf[(size_t)(gm + r) * 384 + gn] = f2bf(vv);
      }
    }
  }
}

// ---------------------------------------------------------------------------
// k_mlp2: GEMM(h1@w2^T)+leaky+GLN-stats | bar | apply -> BF3 (bf16,256)
// grid 512 = 2 n-tiles x 256 m-tiles
// ---------------------------------------------------------------------------
__global__ __launch_bounds__(256, 4) void k_mlp2(
    const unsigned short* __restrict__ A,     // BF2 [NN,384]
    const unsigned short* __restrict__ wb,    // w2b [256,384]
    const float* __restrict__ b2, const float* __restrict__ g2,
    const float* __restrict__ be2,
    unsigned short* __restrict__ outbf,       // BF3 [NN,256]
    float* __restrict__ stat_all, int* bar0)
{
  __shared__ unsigned short As[4096];
  __shared__ unsigned short Bs[4096];
  __shared__ float red[256];
  int tid = threadIdx.x;
  int L = blockIdx.x;
  int bn = (L % 2) * 128;
  int bm = (L / 2) * 128;
  int lane = tid & 63;
  int w = tid >> 6;
  int wm = (w & 1) * 64, wn = (w >> 1) * 64;
  int quad = lane >> 4, r16 = lane & 15;
  f4v acc[4][4] = {};
  gemm_core(A, 384, wb, 384, 384, nullptr, 0, nullptr, 0, 0,
            bm, bn, tid, As, Bs, acc);

  int seg = bm >> 8;
  float lsum = 0.0f, lssq = 0.0f;
#pragma unroll
  for (int mi = 0; mi < 4; ++mi) {
#pragma unroll
    for (int ni = 0; ni < 4; ++ni) {
      int gn = bn + wn + ni * 16 + r16;
      float bv = b2[gn];
#pragma unroll
      for (int r = 0; r < 4; ++r) {
        float v = acc[mi][ni][r] + bv;
        v = (v >= 0.0f) ? v : 0.01f * v;
        acc[mi][ni][r] = v;
        lsum += v;
        lssq += v * v;
      }
    }
  }
  red[tid] = lsum;
  __syncthreads();
  for (int off = 128; off > 0; off >>= 1) {
    if (tid < off) red[tid] += red[tid + off];
    __syncthreads();
  }
  if (tid == 0) atomicAdd(&stat_all[256 + seg], red[0]);
  __syncthreads();
  red[tid] = lssq;
  __syncthreads();
  for (int off = 128; off > 0; off >>= 1) {
    if (tid < off) red[tid] += red[tid + off];
    __syncthreads();
  }
  if (tid == 0) atomicAdd(&stat_all[384 + seg], red[0]);

  grid_bar(bar0, 512);

  float cnt = 256.0f * (float)GIN_;
  float m = stat_all[256 + seg] / cnt;
  float var = stat_all[384 + seg] / cnt - m * m;
  float inv = rsqrtf(var + 1e-5f);
#pragma unroll
  for (int mi = 0; mi < 4; ++mi) {
    int gm = bm + wm + mi * 16 + quad * 4;
#pragma unroll
    for (int ni = 0; ni < 4; ++ni) {
      int gn = bn + wn + ni * 16 + r16;
      float gg = g2[gn], bb = be2[gn];
#pragma unroll
      for (int r = 0; r < 4; ++r) {
        float vv = (acc[mi][ni][r] - m) * inv * gg + bb;
        outbf[(size_t)(gm + r) * 256 + gn] = f2bf(vv);
      }
    }
  }
}

// ---------------------------------------------------------------------------
// k_sage: phaseA aggregate (32 nodes/block) | bar | GEMM 2-phase
// mode 2: +bias, col stats | bar | PairNorm apply+ReLU -> outx (bf16,512)
// mode 3: pooled head -> outp[seg]
// grid 1024; XCD-aware tile decode
// ---------------------------------------------------------------------------
__global__ __launch_bounds__(256, 4) void k_sage(
    const unsigned short* __restrict__ x, int D4log,   // D = 4<<D4log
    unsigned short* __restrict__ aggb,
    const int* __restrict__ offsets, const int* __restrict__ srcs,
    const float* __restrict__ inv_deg,
    const unsigned short* __restrict__ wl, const unsigned short* __restrict__ wr,
    const float* __restrict__ bias, int mode,
    float* __restrict__ cs0, float* __restrict__ cs1,
    unsigned short* __restrict__ outx,
    const float* __restrict__ wc, float* __restrict__ outp,
    int* bar_a, int* bar_b)
{
  __shared__ unsigned short As[4096];
  __shared__ unsigned short Bs[4096];
  __shared__ float red[256];
  __shared__ float cs[128], css[128];
  int tid = threadIdx.x;
  int L = blockIdx.x;
  int D = 4 << D4log;

  // ---- phase A: neighbor-mean for 32 nodes ----
  {
    int D4 = 1 << D4log;              // uint2 lanes per node
    int npb = 256 >> D4log;           // nodes per iteration
    int f4 = tid & (D4 - 1);
    const uint2* xb = (const uint2*)x;
    for (int it = 0; it < 32 / npb * npb; it += npb) {
      int n = L * 32 + it + (tid >> D4log);
      int start = offsets[n], end = offsets[n + 1];
      float wgt = inv_deg[n];
      float a0 = 0.0f, a1 = 0.0f, a2 = 0.0f, a3 = 0.0f;
      for (int e = start; e < end; ++e) {
        uint2 v = xb[((size_t)srcs[e] << D4log) + f4];
        a0 += bf2f((unsigned short)(v.x & 0xffffu));
        a1 += bf2f((unsigned short)(v.x >> 16));
        a2 += bf2f((unsigned short)(v.y & 0xffffu));
        a3 += bf2f((unsigned short)(v.y >> 16));
      }
      uint2 o;
      o.x = ((unsigned)f2bf(a1 * wgt) << 16) | (unsigned)f2bf(a0 * wgt);
      o.y = ((unsigned)f2bf(a3 * wgt) << 16) | (unsigned)f2bf(a2 * wgt);
      ((uint2*)aggb)[((size_t)n << D4log) + f4] = o;
    }
  }
  grid_bar(bar_a, 1024);

  // ---- GEMM ----
  int xcd = L & 7;
  int s = L >> 3;
  int bn = (s & 3) * 128;
  int bm = ((s >> 2) * 8 + xcd) * 128;
  int lane = tid & 63;
  int w = tid >> 6;
  int wm = (w & 1) * 64, wn = (w >> 1) * 64;
  int quad = lane >> 4, r16 = lane & 15;
  f4v acc[4][4] = {};
  gemm_core(aggb, D, wl, D, D, x, D, wr, D, D, bm, bn, tid, As, Bs, acc);

  if (mode == 2) {
    // y = acc + bias back into acc; column sum/ssq
    if (tid < 128) { cs[tid] = 0.0f; css[tid] = 0.0f; }
    __syncthreads();
#pragma unroll
    for (int ni = 0; ni < 4; ++ni) {
      int col = wn + ni * 16 + r16;
      float bv = bias[bn + col];
      float psum = 0.0f, pssq = 0.0f;
#pragma unroll
      for (int mi = 0; mi < 4; ++mi) {
#pragma unroll
        for (int r = 0; r < 4; ++r) {
          float v = acc[mi][ni][r] + bv;
          acc[mi][ni][r] = v;
          psum += v;
          pssq += v * v;
        }
      }
      atomicAdd(&cs[col], psum);
      atomicAdd(&css[col], pssq);
    }
    __syncthreads();
    if (tid < 128) {
      atomicAdd(&cs0[bn + tid], cs[tid]);
      atomicAdd(&cs1[bn + tid], css[tid]);
    }
    grid_bar(bar_b, 1024);

    // finalize: invd over all 512 cols, mu per col; apply + ReLU -> bf16
    const float rN = 1.0f / (float)NN;
    float t = 0.0f;
    for (int c = tid; c < 512; c += 256) {
      float m = cs0[c] * rN;
      t += cs1[c] * rN - m * m;
    }
    red[tid] = t;
    __syncthreads();
    for (int off = 128; off > 0; off >>= 1) {
      if (tid < off) red[tid] += red[tid + off];
      __syncthreads();
    }
    float invd = 1.0f / (1e-5f + sqrtf(fmaxf(red[0], 0.0f)));
    __syncthreads();
#pragma unroll
    for (int mi = 0; mi < 4; ++mi) {
      int gm = bm + wm + mi * 16 + quad * 4;
#pragma unroll
      for (int ni = 0; ni < 4; ++ni) {
        int gn = bn + wn + ni * 16 + r16;
        float mu = cs0[gn] * rN;
#pragma unroll
        for (int r = 0; r < 4; ++r) {
          float vv = fmaxf((acc[mi][ni][r] - mu) * invd, 0.0f);
          outx[(size_t)(gm + r) * GH_ + gn] = f2bf(vv);
        }
      }
    }
  } else {
    // mode 3: pooled head — outp[seg] += sum_rows dot(acc+bias, wc)
    int seg = bm >> 8;
    float part = 0.0f;
#pragma unroll
    for (int ni = 0; ni < 4; ++ni) {
      int gn = bn + wn + ni * 16 + r16;
      float bv = bias[gn];
      float wv = wc[gn];
      float colsum = 0.0f;
#pragma unroll
      for (int mi = 0; mi < 4; ++mi)
#pragma unroll
        for (int r = 0; r < 4; ++r)
          colsum += acc[mi][ni][r] + bv;
      part += colsum * wv;
    }
    red[tid] = part;
    __syncthreads();
    for (int off = 128; off > 0; off >>= 1) {
      if (tid < off) red[tid] += red[tid + off];
      __syncthreads();
    }
    if (tid == 0) atomicAdd(&outp[seg], red[0]);
  }
}

// ---------------------------------------------------------------------------
extern "C" void kernel_launch(void* const* d_in, const int* in_sizes, int n_in,
                              void* d_out, int out_size, void* d_ws, size_t ws_size,
                              hipStream_t stream) {
  const float* node_features = (const float*)d_in[0];
  const float* node_config   = (const float*)d_in[1];
  const float* emb_table     = (const float*)d_in[2];
  const float* w1  = (const float*)d_in[3];
  const float* b1  = (const float*)d_in[4];
  const float* g1  = (const float*)d_in[5];
  const float* be1 = (const float*)d_in[6];
  const float* w2  = (const float*)d_in[7];
  const float* b2  = (const float*)d_in[8];
  const float* g2  = (const float*)d_in[9];
  const float* be2 = (const float*)d_in[10];
  const float* wl1 = (const float*)d_in[11];
  const float* bl1 = (const float*)d_in[12];
  const float* wr1 = (const float*)d_in[13];
  const float* wl2 = (const float*)d_in[14];
  const float* bl2 = (const float*)d_in[15];
  const float* wr2 = (const float*)d_in[16];
  const float* wl3 = (const float*)d_in[17];
  const float* bl3 = (const float*)d_in[18];
  const float* wr3 = (const float*)d_in[19];
  const float* wc  = (const float*)d_in[20];
  const float* bc  = (const float*)d_in[21];
  const int* node_ops = (const int*)d_in[22];
  const int* edges    = (const int*)d_in[23];
  float* out = (float*)d_out;

  char* ws = (char*)d_ws;
  size_t off = 0;
  auto alloc = [&](size_t bytes) -> void* {
    void* p = ws + off;
    off += (bytes + 255) & ~(size_t)255;
    return p;
  };

  // deg_i + cursor + bars contiguous -> single memset
  int*   deg_i   = (int*)alloc(NN * 4);       // 131072 B
  int*   cursor  = (int*)alloc(NN * 4);       // 131072 B
  int*   bars    = (int*)alloc(16 * 4);       // 256 B padded
  int*   offsets = (int*)alloc((NN + 1) * 4);
  int*   srcs    = (int*)alloc(EE * 4);
  int*   bsum    = (int*)alloc(SS * 4);
  int*   boff    = (int*)alloc(SS * 4);
  float* inv_deg = (float*)alloc(NN * 4);
  float* stat_all= (float*)alloc(2560 * 4);
  // bf16 weights (padded)
  unsigned short* w1b  = (unsigned short*)alloc((size_t)384 * 192 * 2);
  unsigned short* w2b  = (unsigned short*)alloc((size_t)256 * 384 * 2);
  unsigned short* wl1b = (unsigned short*)alloc((size_t)512 * 256 * 2);
  unsigned short* wr1b = (unsigned short*)alloc((size_t)512 * 256 * 2);
  unsigned short* wl2b = (unsigned short*)alloc((size_t)512 * 512 * 2);
  unsigned short* wr2b = (unsigned short*)alloc((size_t)512 * 512 * 2);
  unsigned short* wl3b = (unsigned short*)alloc((size_t)512 * 512 * 2);
  unsigned short* wr3b = (unsigned short*)alloc((size_t)512 * 512 * 2);
  // three rotating bf16 slabs
  unsigned short* BF1  = (unsigned short*)alloc((size_t)NN * 512 * 2); // 33.5 MB
  unsigned short* BF2  = (unsigned short*)alloc((size_t)NN * 512 * 2);
  unsigned short* BF3  = (unsigned short*)alloc((size_t)NN * 512 * 2);

  const int* esrc = edges;
  const int* edst = edges + EE;

  // ---- zero deg + cursor + barrier counters (one memset) ----
  hipMemsetAsync(deg_i, 0, (size_t)NN * 4 * 2 + 256, stream);

  // ---- CSR build ----
  deg_count<<<EE / 256, 256, 0, stream>>>(edst, deg_i);
  blk_sum_k<<<NN / 256, 256, 0, stream>>>(deg_i, bsum);
  blk_scan_k<<<1, 128, 0, stream>>>(bsum, boff);
  offsets_k<<<NN / 256, 256, 0, stream>>>(deg_i, boff, offsets, inv_deg);
  bucket_k<<<EE / 256, 256, 0, stream>>>(esrc, edst, offsets, cursor, srcs);

  // ---- MLP layer 1 (prep + GEMM + GLN fused) : BF1=x0 -> BF2 ----
  k_mlp1<<<768, 256, 0, stream>>>(node_features, node_config, emb_table, node_ops,
                                  w1, w2, wl1, wr1, wl2, wr2, wl3, wr3,
                                  w1b, w2b, wl1b, wr1b, wl2b, wr2b, wl3b, wr3b,
                                  BF1, b1, g1, be1, BF2,
                                  stat_all, out, bc, &bars[0], &bars[1]);

  // ---- MLP layer 2 : BF2 -> BF3 ----
  k_mlp2<<<512, 256, 0, stream>>>(BF2, w2b, b2, g2, be2, BF3,
                                  stat_all, &bars[2]);

  // ---- SAGE 1 : x=BF3(256) -> BF2 ----
  k_sage<<<1024, 256, 0, stream>>>(BF3, 6, BF1, offsets, srcs, inv_deg,
                                   wl1b, wr1b, bl1, 2,
                                   stat_all + 512, stat_all + 1024, BF2,
                                   nullptr, nullptr, &bars[3], &bars[4]);

  // ---- SAGE 2 : x=BF2(512) -> BF3 ----
  k_sage<<<1024, 256, 0, stream>>>(BF2, 7, BF1, offsets, srcs, inv_deg,
                                   wl2b, wr2b, bl2, 2,
                                   stat_all + 1536, stat_all + 2048, BF3,
                                   nullptr, nullptr, &bars[5], &bars[6]);

  // ---- SAGE 3 + head : x=BF3(512) -> out ----
  k_sage<<<1024, 256, 0, stream>>>(BF3, 7, BF1, offsets, srcs, inv_deg,
                                   wl3b, wr3b, bl3, 3,
                                   nullptr, nullptr, nullptr,
                                   wc, out, &bars[7], &bars[8]);
}

// Round 7
// 601.559 us; speedup vs baseline: 3.1636x; 3.1636x over previous
//
#include <hip/hip_runtime.h>
#include <hip/hip_bf16.h>

// ---- problem constants (fixed by setup_inputs) ----
#define NN   32768
#define EE   262144
#define SS   128
#define NF_  90
#define NC_  36
#define OD_  64
#define D0_  190
#define DX_  380
#define GIN_ 256
#define GH_  512

typedef __attribute__((ext_vector_type(8))) short  s8v;   // 8 bf16 = 4 VGPRs
typedef __attribute__((ext_vector_type(4))) float  f4v;   // 4 fp32

typedef const __attribute__((address_space(1))) void* gas_ptr;
typedef __attribute__((address_space(3))) void*       las_ptr;

// ---- bf16 helpers (manual, RN) ----
__device__ __forceinline__ float bf2f(unsigned u) {
  return __uint_as_float(u << 16);
}
__device__ __forceinline__ unsigned short f2bf(float f) {
  unsigned u = __float_as_uint(f);
  u += 0x7FFFu + ((u >> 16) & 1u);
  return (unsigned short)(u >> 16);
}
__device__ __forceinline__ unsigned pack2(float a, float b) {
  return ((unsigned)f2bf(b) << 16) | (unsigned)f2bf(a);
}

// ---------------------------------------------------------------------------
// degree / CSR build (parallel 3-phase scan)
// ---------------------------------------------------------------------------
__global__ void deg_count(const int* __restrict__ dst, int* __restrict__ deg) {
  int e = blockIdx.x * 256 + threadIdx.x;
  if (e < EE) atomicAdd(&deg[dst[e]], 1);
}

__global__ __launch_bounds__(256) void blk_sum_k(const int* __restrict__ deg,
                                                 int* __restrict__ bsum) {
  __shared__ int buf[256];
  int tid = threadIdx.x;
  buf[tid] = deg[blockIdx.x * 256 + tid];
  __syncthreads();
  for (int off = 128; off > 0; off >>= 1) {
    if (tid < off) buf[tid] += buf[tid + off];
    __syncthreads();
  }
  if (tid == 0) bsum[blockIdx.x] = buf[0];
}

__global__ __launch_bounds__(128) void blk_scan_k(const int* __restrict__ bsum,
                                                  int* __restrict__ boff) {
  __shared__ int buf[128];
  int tid = threadIdx.x;
  int v = bsum[tid];
  buf[tid] = v;
  __syncthreads();
  for (int d = 1; d < 128; d <<= 1) {
    int t = (tid >= d) ? buf[tid - d] : 0;
    __syncthreads();
    if (tid >= d) buf[tid] += t;
    __syncthreads();
  }
  boff[tid] = buf[tid] - v;   // exclusive
}

__global__ __launch_bounds__(256) void offsets_k(const int* __restrict__ deg,
                                                 const int* __restrict__ boff,
                                                 int* __restrict__ offsets,
                                                 float* __restrict__ inv_deg) {
  __shared__ int buf[256];
  int tid = threadIdx.x;
  int i = blockIdx.x * 256 + tid;
  int v = deg[i];
  buf[tid] = v;
  __syncthreads();
  for (int d = 1; d < 256; d <<= 1) {
    int t = (tid >= d) ? buf[tid - d] : 0;
    __syncthreads();
    if (tid >= d) buf[tid] += t;
    __syncthreads();
  }
  offsets[i] = boff[blockIdx.x] + buf[tid] - v;
  inv_deg[i] = 1.0f / fmaxf((float)v, 1.0f);
  if (i == 0) offsets[NN] = EE;
}

__global__ void bucket_k(const int* __restrict__ src, const int* __restrict__ dst,
                         const int* __restrict__ offsets, int* __restrict__ cursor,
                         int* __restrict__ srcs) {
  int e = blockIdx.x * 256 + threadIdx.x;
  if (e < EE) {
    int d = dst[e];
    int pos = offsets[d] + atomicAdd(&cursor[d], 1);
    srcs[pos] = src[e];
  }
}

// ---------------------------------------------------------------------------
// prep_all: zero stats, init out, convert all weights to bf16, build x0
// ---------------------------------------------------------------------------
#define CW1  73728        // w1b  [384x192]
#define CW2  172032       // w2b  [256x384]
#define CWL1 303104       // wl1b [512x256]
#define CWR1 434176
#define CWL2 696320       // [512x512]
#define CWR2 958464
#define CWL3 1220608
#define CWR3 1482752

__global__ __launch_bounds__(256) void prep_all(
    const float* __restrict__ nf, const float* __restrict__ ncf,
    const float* __restrict__ emb, const int* __restrict__ ops,
    const float* __restrict__ w1, const float* __restrict__ w2,
    const float* __restrict__ wl1, const float* __restrict__ wr1,
    const float* __restrict__ wl2, const float* __restrict__ wr2,
    const float* __restrict__ wl3, const float* __restrict__ wr3,
    unsigned short* __restrict__ w1b, unsigned short* __restrict__ w2b,
    unsigned short* __restrict__ wl1b, unsigned short* __restrict__ wr1b,
    unsigned short* __restrict__ wl2b, unsigned short* __restrict__ wr2b,
    unsigned short* __restrict__ wl3b, unsigned short* __restrict__ wr3b,
    unsigned short* __restrict__ x0,
    float* __restrict__ stat_all, float* __restrict__ outp,
    const float* __restrict__ bc)
{
  const int T = 4096 * 256;
  int gidx = blockIdx.x * 256 + threadIdx.x;
  for (int i = gidx; i < 2560; i += T) stat_all[i] = 0.0f;
  if (gidx < SS) outp[gidx] = bc[0];
  for (int i = gidx; i < CWR3; i += T) {
    if (i < CW1) {
      int r = i / 192, c = i - r * 192;
      w1b[i] = f2bf((r < DX_ && c < D0_) ? w1[r * D0_ + c] : 0.0f);
    } else if (i < CW2) {
      int j = i - CW1;
      int r = j / 384, c = j - r * 384;
      w2b[j] = f2bf((c < DX_) ? w2[r * DX_ + c] : 0.0f);
    } else if (i < CWL1) { int j = i - CW2;  wl1b[j] = f2bf(wl1[j]); }
    else if (i < CWR1)   { int j = i - CWL1; wr1b[j] = f2bf(wr1[j]); }
    else if (i < CWL2)   { int j = i - CWR1; wl2b[j] = f2bf(wl2[j]); }
    else if (i < CWR2)   { int j = i - CWL2; wr2b[j] = f2bf(wr2[j]); }
    else if (i < CWL3)   { int j = i - CWR2; wl3b[j] = f2bf(wl3[j]); }
    else                 { int j = i - CWL3; wr3b[j] = f2bf(wr3[j]); }
  }
  for (int i = gidx; i < NN * 192; i += T) {
    int n = i / 192;
    int c = i - n * 192;
    float v;
    if (c < NF_)            v = nf[n * NF_ + c];
    else if (c < NF_ + NC_) v = ncf[n * NC_ + (c - NF_)];
    else if (c < D0_)       v = emb[ops[n] * OD_ + (c - (NF_ + NC_))];
    else                    v = 0.0f;
    x0[i] = f2bf(v);
  }
}

// ---------------------------------------------------------------------------
// bf16 MFMA GEMM (NT), two-phase: acc = A1*B1^T (+ A2*B2^T)
// 128x128 tile, 256 thr = 4 waves (2x2), each wave 64x64 via 4x4 mfma 16x16x32.
// LDS layout per tile: [koff(4)][row(128)][8 bf16]; async global_load_lds w=16.
// mode 1: C=leaky(acc+bias) fp32, fused scalar (GLN) stats -> st0/st1[seg]
// mode 2: C=acc+bias fp32, fused column (PairNorm) stats -> st0/st1[col]
// mode 3: no C write; outp[seg] += sum_rows dot(acc+bias, wcp)
// swz=1: 1D grid 1024, XCD-aware decode keeping same-bm tiles on one XCD.
// ---------------------------------------------------------------------------
__device__ __forceinline__ void stage_tile_async(const unsigned short* __restrict__ G, int ld,
                                                 int base_row, int k0,
                                                 unsigned short* __restrict__ lds, int tid) {
#pragma unroll
  for (int i = 0; i < 2; ++i) {
    int c = tid + i * 256;        // 0..511
    int row = c & 127;
    int off = c >> 7;             // 0..3 (k chunk of 8 bf16)
    const unsigned short* src = G + (size_t)(base_row + row) * ld + k0 + off * 8;
    unsigned short* dst = lds + off * 1024 + row * 8;
    __builtin_amdgcn_global_load_lds((gas_ptr)(const void*)src, (las_ptr)(void*)dst,
                                     16, 0, 0);
  }
}

__global__ __launch_bounds__(256) void mfma_gemm2(
    const unsigned short* __restrict__ A1, int lda1,
    const unsigned short* __restrict__ B1, int ldb1, int K1,
    const unsigned short* __restrict__ A2, int lda2,
    const unsigned short* __restrict__ B2, int ldb2, int K2,
    const float* __restrict__ bias,
    float* __restrict__ C, int ldc, int Nreal, int mode, int swz,
    float* __restrict__ st0, float* __restrict__ st1,
    const float* __restrict__ wcp, float* __restrict__ outp)
{
  __shared__ unsigned short As[4096];
  __shared__ unsigned short Bs[4096];
  int tid = threadIdx.x;
  int lane = tid & 63;
  int w = tid >> 6;
  int wm = (w & 1) * 64;
  int wn = (w >> 1) * 64;
  int bm, bn;
  if (swz) {
    int L = blockIdx.x;
    int xcd = L & 7;
    int s = L >> 3;
    bn = (s & 3) * 128;
    bm = ((s >> 2) * 8 + xcd) * 128;
  } else {
    bm = blockIdx.y * 128;
    bn = blockIdx.x * 128;
  }
  int quad = lane >> 4;      // 0..3
  int r16 = lane & 15;

  f4v acc[4][4] = {};

#pragma unroll 1
  for (int ph = 0; ph < 2; ++ph) {
    const unsigned short* A = ph ? A2 : A1;
    const unsigned short* B = ph ? B2 : B1;
    int lda = ph ? lda2 : lda1;
    int ldb = ph ? ldb2 : ldb1;
    int K = ph ? K2 : K1;
    for (int k0 = 0; k0 < K; k0 += 32) {
      stage_tile_async(A, lda, bm, k0, As, tid);
      stage_tile_async(B, ldb, bn, k0, Bs, tid);
      __syncthreads();
      s8v af[4], bfr[4];
#pragma unroll
      for (int mi = 0; mi < 4; ++mi)
        af[mi] = *(const s8v*)&As[quad * 1024 + (wm + mi * 16 + r16) * 8];
#pragma unroll
      for (int ni = 0; ni < 4; ++ni)
        bfr[ni] = *(const s8v*)&Bs[quad * 1024 + (wn + ni * 16 + r16) * 8];
#pragma unroll
      for (int mi = 0; mi < 4; ++mi)
#pragma unroll
        for (int ni = 0; ni < 4; ++ni)
          acc[mi][ni] = __builtin_amdgcn_mfma_f32_16x16x32_bf16(
              af[mi], bfr[ni], acc[mi][ni], 0, 0, 0);
      __syncthreads();
    }
  }

  // epilogue scratch overlays the (now dead) staging LDS
  float* red = (float*)As;            // 256 floats
  float* cs  = (float*)Bs;            // 128 floats
  float* css = ((float*)Bs) + 128;    // 128 floats

  int seg = bm >> 8;

  if (mode == 1) {
    float lsum = 0.0f, lssq = 0.0f;
#pragma unroll
    for (int mi = 0; mi < 4; ++mi) {
      int gm = bm + wm + mi * 16 + quad * 4;
#pragma unroll
      for (int ni = 0; ni < 4; ++ni) {
        int gn = bn + wn + ni * 16 + r16;
        if (gn < Nreal) {
          float bv = bias[gn];
#pragma unroll
          for (int r = 0; r < 4; ++r) {
            float v = acc[mi][ni][r] + bv;
            v = (v >= 0.0f) ? v : 0.01f * v;
            C[(size_t)(gm + r) * ldc + gn] = v;
            lsum += v;
            lssq += v * v;
          }
        }
      }
    }
    red[tid] = lsum;
    __syncthreads();
    for (int off = 128; off > 0; off >>= 1) {
      if (tid < off) red[tid] += red[tid + off];
      __syncthreads();
    }
    if (tid == 0) atomicAdd(&st0[seg], red[0]);
    __syncthreads();
    red[tid] = lssq;
    __syncthreads();
    for (int off = 128; off > 0; off >>= 1) {
      if (tid < off) red[tid] += red[tid + off];
      __syncthreads();
    }
    if (tid == 0) atomicAdd(&st1[seg], red[0]);
  } else if (mode == 2) {
    if (tid < 128) { cs[tid] = 0.0f; css[tid] = 0.0f; }
    __syncthreads();
#pragma unroll
    for (int ni = 0; ni < 4; ++ni) {
      int col = wn + ni * 16 + r16;       // 0..127
      int gn = bn + col;
      float bv = bias[gn];
      float psum = 0.0f, pssq = 0.0f;
#pragma unroll
      for (int mi = 0; mi < 4; ++mi) {
        int gm = bm + wm + mi * 16 + quad * 4;
#pragma unroll
        for (int r = 0; r < 4; ++r) {
          float v = acc[mi][ni][r] + bv;
          C[(size_t)(gm + r) * ldc + gn] = v;
          psum += v;
          pssq += v * v;
        }
      }
      atomicAdd(&cs[col], psum);
      atomicAdd(&css[col], pssq);
    }
    __syncthreads();
    if (tid < 128) {
      atomicAdd(&st0[bn + tid], cs[tid]);
      atomicAdd(&st1[bn + tid], css[tid]);
    }
  } else {
    // mode 3: pooled head — outp[seg] += sum_rows dot(acc+bias, wc)
    float part = 0.0f;
#pragma unroll
    for (int ni = 0; ni < 4; ++ni) {
      int gn = bn + wn + ni * 16 + r16;
      float bv = bias[gn];
      float wv = wcp[gn];
      float colsum = 0.0f;
#pragma unroll
      for (int mi = 0; mi < 4; ++mi)
#pragma unroll
        for (int r = 0; r < 4; ++r)
          colsum += acc[mi][ni][r] + bv;
      part += colsum * wv;
    }
    red[tid] = part;
    __syncthreads();
    for (int off = 128; off > 0; off >>= 1) {
      if (tid < off) red[tid] += red[tid + off];
      __syncthreads();
    }
    if (tid == 0) atomicAdd(&outp[seg], red[0]);
  }
}

// ---------------------------------------------------------------------------
// GLN apply (finalize folded in): x fp32 -> bf16 padded
// ---------------------------------------------------------------------------
__global__ __launch_bounds__(256) void gln_apply_bf16(
    const float* __restrict__ x, int ld, int D, int Dp,
    const float* __restrict__ seg_sum, const float* __restrict__ seg_ssq,
    const float* __restrict__ g, const float* __restrict__ be,
    unsigned short* __restrict__ out) {
  int r = blockIdx.x;
  int s = r >> 8;
  float cnt = 256.0f * (float)D;
  float m = seg_sum[s] / cnt;
  float var = seg_ssq[s] / cnt - m * m;
  float inv = rsqrtf(var + 1e-5f);
  const float* row = x + (size_t)r * ld;
  unsigned short* orow = out + (size_t)r * Dp;
  for (int c = threadIdx.x; c < Dp; c += 256) {
    float v = (c < D) ? ((row[c] - m) * inv * g[c] + be[c]) : 0.0f;
    orow[c] = f2bf(v);
  }
}

// ---------------------------------------------------------------------------
// neighbor-mean aggregation: uint4 (8 bf16 = 16B) per lane
// L8 = log2(uint4 lanes per node); nodes per 256-thr block = 256>>L8
// ---------------------------------------------------------------------------
__global__ __launch_bounds__(256) void aggregate8(const unsigned short* __restrict__ x,
                                                  int L8,
                                                  unsigned short* __restrict__ agg,
                                                  const int* __restrict__ offsets,
                                                  const int* __restrict__ srcs,
                                                  const float* __restrict__ inv_deg) {
  int tid = threadIdx.x;
  int n = (blockIdx.x << (8 - L8)) + (tid >> L8);
  int f8 = tid & ((1 << L8) - 1);
  int start = offsets[n], end = offsets[n + 1];
  float wgt = inv_deg[n];
  const uint4* xb = (const uint4*)x;
  float a0 = 0, a1 = 0, a2 = 0, a3 = 0, a4 = 0, a5 = 0, a6 = 0, a7 = 0;
  for (int e = start; e < end; ++e) {
    uint4 v = xb[((size_t)srcs[e] << L8) + f8];
    a0 += bf2f(v.x & 0xffffu); a1 += bf2f(v.x >> 16);
    a2 += bf2f(v.y & 0xffffu); a3 += bf2f(v.y >> 16);
    a4 += bf2f(v.z & 0xffffu); a5 += bf2f(v.z >> 16);
    a6 += bf2f(v.w & 0xffffu); a7 += bf2f(v.w >> 16);
  }
  uint4 o;
  o.x = pack2(a0 * wgt, a1 * wgt);
  o.y = pack2(a2 * wgt, a3 * wgt);
  o.z = pack2(a4 * wgt, a5 * wgt);
  o.w = pack2(a6 * wgt, a7 * wgt);
  ((uint4*)agg)[((size_t)n << L8) + f8] = o;
}

// ---------------------------------------------------------------------------
// PairNorm finalize + vectorized apply (float4 in, uint2 out, +ReLU)
// ---------------------------------------------------------------------------
__global__ __launch_bounds__(512) void pn_finalize(const float* __restrict__ colsum,
                                                   const float* __restrict__ colssq,
                                                   float* __restrict__ mu,
                                                   float* __restrict__ invd) {
  int f = threadIdx.x;
  float m = colsum[f] / (float)NN;
  mu[f] = m;
  float t = colssq[f] / (float)NN - m * m;
  __shared__ float buf[512];
  buf[f] = t;
  __syncthreads();
  for (int off = 256; off > 0; off >>= 1) {
    if (f < off) buf[f] += buf[f + off];
    __syncthreads();
  }
  if (f == 0) invd[0] = 1.0f / (1e-5f + sqrtf(fmaxf(buf[0], 0.0f)));
}

__global__ __launch_bounds__(128) void pn_apply_v(const float* __restrict__ y,
                                                  const float* __restrict__ mu,
                                                  const float* __restrict__ invd,
                                                  unsigned short* __restrict__ xb) {
  int r = blockIdx.x;
  int f4 = threadIdx.x;             // 0..127
  float id = invd[0];
  float4 v = ((const float4*)(y + (size_t)r * GH_))[f4];
  float4 m = ((const float4*)mu)[f4];
  float v0 = fmaxf((v.x - m.x) * id, 0.0f);
  float v1 = fmaxf((v.y - m.y) * id, 0.0f);
  float v2 = fmaxf((v.z - m.z) * id, 0.0f);
  float v3 = fmaxf((v.w - m.w) * id, 0.0f);
  uint2 o;
  o.x = pack2(v0, v1);
  o.y = pack2(v2, v3);
  ((uint2*)(xb + (size_t)r * GH_))[f4] = o;
}

// ---------------------------------------------------------------------------
extern "C" void kernel_launch(void* const* d_in, const int* in_sizes, int n_in,
                              void* d_out, int out_size, void* d_ws, size_t ws_size,
                              hipStream_t stream) {
  const float* node_features = (const float*)d_in[0];
  const float* node_config   = (const float*)d_in[1];
  const float* emb_table     = (const float*)d_in[2];
  const float* w1  = (const float*)d_in[3];
  const float* b1  = (const float*)d_in[4];
  const float* g1  = (const float*)d_in[5];
  const float* be1 = (const float*)d_in[6];
  const float* w2  = (const float*)d_in[7];
  const float* b2  = (const float*)d_in[8];
  const float* g2  = (const float*)d_in[9];
  const float* be2 = (const float*)d_in[10];
  const float* wl1 = (const float*)d_in[11];
  const float* bl1 = (const float*)d_in[12];
  const float* wr1 = (const float*)d_in[13];
  const float* wl2 = (const float*)d_in[14];
  const float* bl2 = (const float*)d_in[15];
  const float* wr2 = (const float*)d_in[16];
  const float* wl3 = (const float*)d_in[17];
  const float* bl3 = (const float*)d_in[18];
  const float* wr3 = (const float*)d_in[19];
  const float* wc  = (const float*)d_in[20];
  const float* bc  = (const float*)d_in[21];
  const int* node_ops = (const int*)d_in[22];
  const int* edges    = (const int*)d_in[23];
  float* out = (float*)d_out;

  char* ws = (char*)d_ws;
  size_t off = 0;
  auto alloc = [&](size_t bytes) -> void* {
    void* p = ws + off;
    off += (bytes + 255) & ~(size_t)255;
    return p;
  };

  // deg_i + cursor contiguous -> single memset
  int*   deg_i   = (int*)alloc(NN * 4);
  int*   cursor  = (int*)alloc(NN * 4);
  int*   offsets = (int*)alloc((NN + 1) * 4);
  int*   srcs    = (int*)alloc(EE * 4);
  int*   bsum    = (int*)alloc(SS * 4);
  int*   boff    = (int*)alloc(SS * 4);
  float* inv_deg = (float*)alloc(NN * 4);
  float* stat_all= (float*)alloc(2560 * 4);
  float* mu      = (float*)alloc(512 * 4);
  float* invd    = (float*)alloc(256);
  // bf16 weights (padded)
  unsigned short* w1b  = (unsigned short*)alloc((size_t)384 * 192 * 2);
  unsigned short* w2b  = (unsigned short*)alloc((size_t)256 * 384 * 2);
  unsigned short* wl1b = (unsigned short*)alloc((size_t)512 * 256 * 2);
  unsigned short* wr1b = (unsigned short*)alloc((size_t)512 * 256 * 2);
  unsigned short* wl2b = (unsigned short*)alloc((size_t)512 * 512 * 2);
  unsigned short* wr2b = (unsigned short*)alloc((size_t)512 * 512 * 2);
  unsigned short* wl3b = (unsigned short*)alloc((size_t)512 * 512 * 2);
  unsigned short* wr3b = (unsigned short*)alloc((size_t)512 * 512 * 2);
  // fp32 GEMM output slab + three rotating bf16 slabs
  float*          Y    = (float*)alloc((size_t)NN * 512 * 4);          // 67 MB
  unsigned short* BF1  = (unsigned short*)alloc((size_t)NN * 512 * 2); // 33.5 MB
  unsigned short* BF2  = (unsigned short*)alloc((size_t)NN * 512 * 2);
  unsigned short* BF3  = (unsigned short*)alloc((size_t)NN * 512 * 2);

  const int* esrc = edges;
  const int* edst = edges + EE;

  // stat_all regions: gln1 s[0,128) q[128,256) | gln2 s[256,384) q[384,512)
  //                   pn1 cs0[512,1024) cs1[1024,1536) | pn2 cs0[1536,2048) cs1[2048,2560)
  float* gln1s = stat_all;       float* gln1q = stat_all + 128;
  float* gln2s = stat_all + 256; float* gln2q = stat_all + 384;
  float* pn1s  = stat_all + 512; float* pn1q  = stat_all + 1024;
  float* pn2s  = stat_all + 1536; float* pn2q = stat_all + 2048;

  // ---- zero deg + cursor (one memset) ----
  hipMemsetAsync(deg_i, 0, (size_t)NN * 4 * 2, stream);

  // ---- CSR build ----
  deg_count<<<EE / 256, 256, 0, stream>>>(edst, deg_i);
  blk_sum_k<<<NN / 256, 256, 0, stream>>>(deg_i, bsum);
  blk_scan_k<<<1, 128, 0, stream>>>(bsum, boff);
  offsets_k<<<NN / 256, 256, 0, stream>>>(deg_i, boff, offsets, inv_deg);
  bucket_k<<<EE / 256, 256, 0, stream>>>(esrc, edst, offsets, cursor, srcs);

  // ---- prep: stats zero, out init, weights, x0 (BF1) ----
  prep_all<<<4096, 256, 0, stream>>>(node_features, node_config, emb_table, node_ops,
                                     w1, w2, wl1, wr1, wl2, wr2, wl3, wr3,
                                     w1b, w2b, wl1b, wr1b, wl2b, wr2b, wl3b, wr3b,
                                     BF1, stat_all, out, bc);

  // ---- MLP layer 1: Y = leaky(x0@w1^T+b1) + GLN stats; apply -> BF2 ----
  {
    dim3 g(3, 256);
    mfma_gemm2<<<g, 256, 0, stream>>>(BF1, 192, w1b, 192, 192,
                                      nullptr, 0, nullptr, 0, 0,
                                      b1, Y, 384, DX_, 1, 0,
                                      gln1s, gln1q, nullptr, nullptr);
  }
  gln_apply_bf16<<<NN, 256, 0, stream>>>(Y, 384, DX_, 384, gln1s, gln1q, g1, be1, BF2);

  // ---- MLP layer 2: Y = leaky(h1@w2^T+b2) + GLN stats; apply -> BF3 ----
  {
    dim3 g(2, 256);
    mfma_gemm2<<<g, 256, 0, stream>>>(BF2, 384, w2b, 384, 384,
                                      nullptr, 0, nullptr, 0, 0,
                                      b2, Y, 256, GIN_, 1, 0,
                                      gln2s, gln2q, nullptr, nullptr);
  }
  gln_apply_bf16<<<NN, 256, 0, stream>>>(Y, 256, GIN_, 256, gln2s, gln2q, g2, be2, BF3);

  // ---- SAGE 1: agg(BF1) <- h2(BF3, D=256); Y = agg@wl1 + h2@wr1 (+col stats) ----
  aggregate8<<<NN / 8, 256, 0, stream>>>(BF3, 5, BF1, offsets, srcs, inv_deg);
  mfma_gemm2<<<1024, 256, 0, stream>>>(BF1, 256, wl1b, 256, 256,
                                       BF3, 256, wr1b, 256, 256,
                                       bl1, Y, 512, GH_, 2, 1,
                                       pn1s, pn1q, nullptr, nullptr);
  pn_finalize<<<1, 512, 0, stream>>>(pn1s, pn1q, mu, invd);
  pn_apply_v<<<NN, 128, 0, stream>>>(Y, mu, invd, BF2);   // x1 -> BF2

  // ---- SAGE 2: agg(BF1) <- x1(BF2, D=512) ----
  aggregate8<<<NN / 4, 256, 0, stream>>>(BF2, 6, BF1, offsets, srcs, inv_deg);
  mfma_gemm2<<<1024, 256, 0, stream>>>(BF1, 512, wl2b, 512, 512,
                                       BF2, 512, wr2b, 512, 512,
                                       bl2, Y, 512, GH_, 2, 1,
                                       pn2s, pn2q, nullptr, nullptr);
  pn_finalize<<<1, 512, 0, stream>>>(pn2s, pn2q, mu, invd);
  pn_apply_v<<<NN, 128, 0, stream>>>(Y, mu, invd, BF3);   // x2 -> BF3

  // ---- SAGE 3 + head: agg(BF1) <- x2(BF3); out[seg] += pooled head ----
  aggregate8<<<NN / 4, 256, 0, stream>>>(BF3, 6, BF1, offsets, srcs, inv_deg);
  mfma_gemm2<<<1024, 256, 0, stream>>>(BF1, 512, wl3b, 512, 512,
                                       BF3, 512, wr3b, 512, 512,
                                       bl3, nullptr, 512, GH_, 3, 1,
                                       nullptr, nullptr, wc, out);
}

// Round 8
// 584.605 us; speedup vs baseline: 3.2553x; 1.0290x over previous
//
#include <hip/hip_runtime.h>
#include <hip/hip_bf16.h>

// ---- problem constants (fixed by setup_inputs) ----
#define NN   32768
#define EE   262144
#define SS   128
#define NF_  90
#define NC_  36
#define OD_  64
#define D0_  190
#define DX_  380
#define GIN_ 256
#define GH_  512

typedef __attribute__((ext_vector_type(8))) short  s8v;   // 8 bf16 = 4 VGPRs
typedef __attribute__((ext_vector_type(4))) float  f4v;   // 4 fp32

typedef const __attribute__((address_space(1))) void* gas_ptr;
typedef __attribute__((address_space(3))) void*       las_ptr;

// ---- bf16 helpers (manual, RN) ----
__device__ __forceinline__ float bf2f(unsigned u) {
  return __uint_as_float(u << 16);
}
__device__ __forceinline__ unsigned short f2bf(float f) {
  unsigned u = __float_as_uint(f);
  u += 0x7FFFu + ((u >> 16) & 1u);
  return (unsigned short)(u >> 16);
}
__device__ __forceinline__ unsigned pack2(float a, float b) {
  return ((unsigned)f2bf(b) << 16) | (unsigned)f2bf(a);
}

// ---------------------------------------------------------------------------
// degree / CSR build (parallel 3-phase scan)
// ---------------------------------------------------------------------------
__global__ void deg_count(const int* __restrict__ dst, int* __restrict__ deg) {
  int e = blockIdx.x * 256 + threadIdx.x;
  if (e < EE) atomicAdd(&deg[dst[e]], 1);
}

__global__ __launch_bounds__(256) void blk_sum_k(const int* __restrict__ deg,
                                                 int* __restrict__ bsum) {
  __shared__ int buf[256];
  int tid = threadIdx.x;
  buf[tid] = deg[blockIdx.x * 256 + tid];
  __syncthreads();
  for (int off = 128; off > 0; off >>= 1) {
    if (tid < off) buf[tid] += buf[tid + off];
    __syncthreads();
  }
  if (tid == 0) bsum[blockIdx.x] = buf[0];
}

__global__ __launch_bounds__(128) void blk_scan_k(const int* __restrict__ bsum,
                                                  int* __restrict__ boff) {
  __shared__ int buf[128];
  int tid = threadIdx.x;
  int v = bsum[tid];
  buf[tid] = v;
  __syncthreads();
  for (int d = 1; d < 128; d <<= 1) {
    int t = (tid >= d) ? buf[tid - d] : 0;
    __syncthreads();
    if (tid >= d) buf[tid] += t;
    __syncthreads();
  }
  boff[tid] = buf[tid] - v;   // exclusive
}

__global__ __launch_bounds__(256) void offsets_k(const int* __restrict__ deg,
                                                 const int* __restrict__ boff,
                                                 int* __restrict__ offsets,
                                                 float* __restrict__ inv_deg) {
  __shared__ int buf[256];
  int tid = threadIdx.x;
  int i = blockIdx.x * 256 + tid;
  int v = deg[i];
  buf[tid] = v;
  __syncthreads();
  for (int d = 1; d < 256; d <<= 1) {
    int t = (tid >= d) ? buf[tid - d] : 0;
    __syncthreads();
    if (tid >= d) buf[tid] += t;
    __syncthreads();
  }
  offsets[i] = boff[blockIdx.x] + buf[tid] - v;
  inv_deg[i] = 1.0f / fmaxf((float)v, 1.0f);
  if (i == 0) offsets[NN] = EE;
}

__global__ void bucket_k(const int* __restrict__ src, const int* __restrict__ dst,
                         const int* __restrict__ offsets, int* __restrict__ cursor,
                         int* __restrict__ srcs) {
  int e = blockIdx.x * 256 + threadIdx.x;
  if (e < EE) {
    int d = dst[e];
    int pos = offsets[d] + atomicAdd(&cursor[d], 1);
    srcs[pos] = src[e];
  }
}

// ---------------------------------------------------------------------------
// prep_all: zero stats, init out, convert+pack all weights to bf16, build x0
// packed SAGE weights: WC[j] = [wl[j] | wr[j]]
// ---------------------------------------------------------------------------
#define P1 73728          // w1b  [384x192]
#define P2 172032         // w2b  [256x384]
#define P3 434176         // WC1  [512x512]
#define P4 958464         // WC2  [512x1024]
#define P5 1482752        // WC3  [512x1024]

__global__ __launch_bounds__(256) void prep_all(
    const float* __restrict__ nf, const float* __restrict__ ncf,
    const float* __restrict__ emb, const int* __restrict__ ops,
    const float* __restrict__ w1, const float* __restrict__ w2,
    const float* __restrict__ wl1, const float* __restrict__ wr1,
    const float* __restrict__ wl2, const float* __restrict__ wr2,
    const float* __restrict__ wl3, const float* __restrict__ wr3,
    unsigned short* __restrict__ w1b, unsigned short* __restrict__ w2b,
    unsigned short* __restrict__ wc1, unsigned short* __restrict__ wc2,
    unsigned short* __restrict__ wc3,
    unsigned short* __restrict__ x0,
    float* __restrict__ stat_all, float* __restrict__ outp,
    const float* __restrict__ bc)
{
  const int T = 4096 * 256;
  int gidx = blockIdx.x * 256 + threadIdx.x;
  for (int i = gidx; i < 2560; i += T) stat_all[i] = 0.0f;
  if (gidx < SS) outp[gidx] = bc[0];
  for (int i = gidx; i < P5; i += T) {
    if (i < P1) {
      int r = i / 192, c = i - r * 192;
      w1b[i] = f2bf((r < DX_ && c < D0_) ? w1[r * D0_ + c] : 0.0f);
    } else if (i < P2) {
      int j = i - P1;
      int r = j / 384, c = j - r * 384;
      w2b[j] = f2bf((c < DX_) ? w2[r * DX_ + c] : 0.0f);
    } else if (i < P3) {
      int j = i - P2;                 // [0, 512*512)
      int r = j >> 9, c = j & 511;
      wc1[j] = f2bf((c < 256) ? wl1[r * 256 + c] : wr1[r * 256 + (c - 256)]);
    } else if (i < P4) {
      int j = i - P3;                 // [0, 512*1024)
      int r = j >> 10, c = j & 1023;
      wc2[j] = f2bf((c < 512) ? wl2[r * 512 + c] : wr2[r * 512 + (c - 512)]);
    } else {
      int j = i - P4;
      int r = j >> 10, c = j & 1023;
      wc3[j] = f2bf((c < 512) ? wl3[r * 512 + c] : wr3[r * 512 + (c - 512)]);
    }
  }
  for (int i = gidx; i < NN * 192; i += T) {
    int n = i / 192;
    int c = i - n * 192;
    float v;
    if (c < NF_)            v = nf[n * NF_ + c];
    else if (c < NF_ + NC_) v = ncf[n * NC_ + (c - NF_)];
    else if (c < D0_)       v = emb[ops[n] * OD_ + (c - (NF_ + NC_))];
    else                    v = 0.0f;
    x0[i] = f2bf(v);
  }
}

// ---------------------------------------------------------------------------
// bf16 MFMA GEMM (NT), single-phase, BK=64: acc = A*B^T
// 128x128 tile, 256 thr = 4 waves (2x2), each wave 64x64 via 4x4 mfma 16x16x32.
// LDS: [koff(8)][row(128)][8 bf16] per matrix = 16 KB each, 32 KB total.
// mode 1: C=leaky(acc+bias) fp32, fused scalar (GLN) stats -> st0/st1[seg]
// mode 2: C=acc+bias fp32, fused column (PairNorm) stats -> st0/st1[col]
// mode 3: no C write; outp[seg] += sum_rows dot(acc+bias, wcp)
// swz=1: 1D grid 1024, XCD-aware decode keeping same-bm tiles on one XCD.
// ---------------------------------------------------------------------------
__device__ __forceinline__ void stage64(const unsigned short* __restrict__ G, int ld,
                                        int base_row, int k0,
                                        unsigned short* __restrict__ lds, int tid) {
#pragma unroll
  for (int i = 0; i < 4; ++i) {
    int c = tid + i * 256;        // 0..1023
    int row = c & 127;
    int koff = c >> 7;            // 0..7 (k chunk of 8 bf16)
    const unsigned short* src = G + (size_t)(base_row + row) * ld + k0 + koff * 8;
    unsigned short* dst = lds + koff * 1024 + row * 8;
    __builtin_amdgcn_global_load_lds((gas_ptr)(const void*)src, (las_ptr)(void*)dst,
                                     16, 0, 0);
  }
}

__global__ __launch_bounds__(256) void mfma_gemm(
    const unsigned short* __restrict__ A, int lda,
    const unsigned short* __restrict__ B, int ldb, int K,
    const float* __restrict__ bias,
    float* __restrict__ C, int ldc, int Nreal, int mode, int swz,
    float* __restrict__ st0, float* __restrict__ st1,
    const float* __restrict__ wcp, float* __restrict__ outp)
{
  __shared__ unsigned short As[8192];
  __shared__ unsigned short Bs[8192];
  int tid = threadIdx.x;
  int lane = tid & 63;
  int w = tid >> 6;
  int wm = (w & 1) * 64;
  int wn = (w >> 1) * 64;
  int bm, bn;
  if (swz) {
    int L = blockIdx.x;
    int xcd = L & 7;
    int s = L >> 3;
    bn = (s & 3) * 128;
    bm = ((s >> 2) * 8 + xcd) * 128;
  } else {
    bm = blockIdx.y * 128;
    bn = blockIdx.x * 128;
  }
  int quad = lane >> 4;      // 0..3
  int r16 = lane & 15;

  f4v acc[4][4] = {};

  for (int k0 = 0; k0 < K; k0 += 64) {
    stage64(A, lda, bm, k0, As, tid);
    stage64(B, ldb, bn, k0, Bs, tid);
    __syncthreads();
#pragma unroll
    for (int s = 0; s < 2; ++s) {
      s8v af[4], bfr[4];
#pragma unroll
      for (int mi = 0; mi < 4; ++mi)
        af[mi] = *(const s8v*)&As[(s * 4 + quad) * 1024 + (wm + mi * 16 + r16) * 8];
#pragma unroll
      for (int ni = 0; ni < 4; ++ni)
        bfr[ni] = *(const s8v*)&Bs[(s * 4 + quad) * 1024 + (wn + ni * 16 + r16) * 8];
#pragma unroll
      for (int mi = 0; mi < 4; ++mi)
#pragma unroll
        for (int ni = 0; ni < 4; ++ni)
          acc[mi][ni] = __builtin_amdgcn_mfma_f32_16x16x32_bf16(
              af[mi], bfr[ni], acc[mi][ni], 0, 0, 0);
    }
    __syncthreads();
  }

  // epilogue scratch overlays the (now dead) staging LDS
  float* red = (float*)As;            // 256 floats
  float* cs  = (float*)Bs;            // 128 floats
  float* css = ((float*)Bs) + 128;    // 128 floats

  int seg = bm >> 8;

  if (mode == 1) {
    float lsum = 0.0f, lssq = 0.0f;
#pragma unroll
    for (int mi = 0; mi < 4; ++mi) {
      int gm = bm + wm + mi * 16 + quad * 4;
#pragma unroll
      for (int ni = 0; ni < 4; ++ni) {
        int gn = bn + wn + ni * 16 + r16;
        if (gn < Nreal) {
          float bv = bias[gn];
#pragma unroll
          for (int r = 0; r < 4; ++r) {
            float v = acc[mi][ni][r] + bv;
            v = (v >= 0.0f) ? v : 0.01f * v;
            C[(size_t)(gm + r) * ldc + gn] = v;
            lsum += v;
            lssq += v * v;
          }
        }
      }
    }
    red[tid] = lsum;
    __syncthreads();
    for (int off = 128; off > 0; off >>= 1) {
      if (tid < off) red[tid] += red[tid + off];
      __syncthreads();
    }
    if (tid == 0) atomicAdd(&st0[seg], red[0]);
    __syncthreads();
    red[tid] = lssq;
    __syncthreads();
    for (int off = 128; off > 0; off >>= 1) {
      if (tid < off) red[tid] += red[tid + off];
      __syncthreads();
    }
    if (tid == 0) atomicAdd(&st1[seg], red[0]);
  } else if (mode == 2) {
    if (tid < 128) { cs[tid] = 0.0f; css[tid] = 0.0f; }
    __syncthreads();
#pragma unroll
    for (int ni = 0; ni < 4; ++ni) {
      int col = wn + ni * 16 + r16;       // 0..127
      int gn = bn + col;
      float bv = bias[gn];
      float psum = 0.0f, pssq = 0.0f;
#pragma unroll
      for (int mi = 0; mi < 4; ++mi) {
        int gm = bm + wm + mi * 16 + quad * 4;
#pragma unroll
        for (int r = 0; r < 4; ++r) {
          float v = acc[mi][ni][r] + bv;
          C[(size_t)(gm + r) * ldc + gn] = v;
          psum += v;
          pssq += v * v;
        }
      }
      atomicAdd(&cs[col], psum);
      atomicAdd(&css[col], pssq);
    }
    __syncthreads();
    if (tid < 128) {
      atomicAdd(&st0[bn + tid], cs[tid]);
      atomicAdd(&st1[bn + tid], css[tid]);
    }
  } else {
    // mode 3: pooled head — outp[seg] += sum_rows dot(acc+bias, wc)
    float part = 0.0f;
#pragma unroll
    for (int ni = 0; ni < 4; ++ni) {
      int gn = bn + wn + ni * 16 + r16;
      float bv = bias[gn];
      float wv = wcp[gn];
      float colsum = 0.0f;
#pragma unroll
      for (int mi = 0; mi < 4; ++mi)
#pragma unroll
        for (int r = 0; r < 4; ++r)
          colsum += acc[mi][ni][r] + bv;
      part += colsum * wv;
    }
    red[tid] = part;
    __syncthreads();
    for (int off = 128; off > 0; off >>= 1) {
      if (tid < off) red[tid] += red[tid + off];
      __syncthreads();
    }
    if (tid == 0) atomicAdd(&outp[seg], red[0]);
  }
}

// ---------------------------------------------------------------------------
// GLN apply (finalize folded in): Y fp32 -> bf16, written at column offset co
// of a row of ldo elements
// ---------------------------------------------------------------------------
__global__ __launch_bounds__(256) void gln_apply_bf16(
    const float* __restrict__ x, int ld, int D, int Dp,
    const float* __restrict__ seg_sum, const float* __restrict__ seg_ssq,
    const float* __restrict__ g, const float* __restrict__ be,
    unsigned short* __restrict__ out, int ldo, int co) {
  int r = blockIdx.x;
  int s = r >> 8;
  float cnt = 256.0f * (float)D;
  float m = seg_sum[s] / cnt;
  float var = seg_ssq[s] / cnt - m * m;
  float inv = rsqrtf(var + 1e-5f);
  const float* row = x + (size_t)r * ld;
  unsigned short* orow = out + (size_t)r * ldo + co;
  for (int c = threadIdx.x; c < Dp; c += 256) {
    float v = (c < D) ? ((row[c] - m) * inv * g[c] + be[c]) : 0.0f;
    orow[c] = f2bf(v);
  }
}

// ---------------------------------------------------------------------------
// neighbor-mean aggregation: uint4 (8 bf16 = 16B) per lane, edge loop x2.
// Reads x rows at uint4 offset (r*ldu4 + cb4), writes agg at (n*ldu4 + cba4).
// L8 = log2(uint4 lanes per node); nodes per 256-thr block = 256>>L8
// ---------------------------------------------------------------------------
__global__ __launch_bounds__(256) void aggregate8(
    const unsigned short* __restrict__ xs, int ldu4, int cb4, int cba4, int L8,
    unsigned short* __restrict__ aggs,
    const int* __restrict__ offsets, const int* __restrict__ srcs,
    const float* __restrict__ inv_deg) {
  int tid = threadIdx.x;
  int n = (blockIdx.x << (8 - L8)) + (tid >> L8);
  int f8 = tid & ((1 << L8) - 1);
  int start = offsets[n], end = offsets[n + 1];
  float wgt = inv_deg[n];
  const uint4* xb = (const uint4*)xs;
  float a0 = 0, a1 = 0, a2 = 0, a3 = 0, a4 = 0, a5 = 0, a6 = 0, a7 = 0;
  int e = start;
  for (; e + 2 <= end; e += 2) {
    uint4 v = xb[(size_t)srcs[e] * ldu4 + cb4 + f8];
    uint4 u = xb[(size_t)srcs[e + 1] * ldu4 + cb4 + f8];
    a0 += bf2f(v.x & 0xffffu); a1 += bf2f(v.x >> 16);
    a2 += bf2f(v.y & 0xffffu); a3 += bf2f(v.y >> 16);
    a4 += bf2f(v.z & 0xffffu); a5 += bf2f(v.z >> 16);
    a6 += bf2f(v.w & 0xffffu); a7 += bf2f(v.w >> 16);
    a0 += bf2f(u.x & 0xffffu); a1 += bf2f(u.x >> 16);
    a2 += bf2f(u.y & 0xffffu); a3 += bf2f(u.y >> 16);
    a4 += bf2f(u.z & 0xffffu); a5 += bf2f(u.z >> 16);
    a6 += bf2f(u.w & 0xffffu); a7 += bf2f(u.w >> 16);
  }
  if (e < end) {
    uint4 v = xb[(size_t)srcs[e] * ldu4 + cb4 + f8];
    a0 += bf2f(v.x & 0xffffu); a1 += bf2f(v.x >> 16);
    a2 += bf2f(v.y & 0xffffu); a3 += bf2f(v.y >> 16);
    a4 += bf2f(v.z & 0xffffu); a5 += bf2f(v.z >> 16);
    a6 += bf2f(v.w & 0xffffu); a7 += bf2f(v.w >> 16);
  }
  uint4 o;
  o.x = pack2(a0 * wgt, a1 * wgt);
  o.y = pack2(a2 * wgt, a3 * wgt);
  o.z = pack2(a4 * wgt, a5 * wgt);
  o.w = pack2(a6 * wgt, a7 * wgt);
  ((uint4*)aggs)[(size_t)n * ldu4 + cba4 + f8] = o;
}

// ---------------------------------------------------------------------------
// PairNorm finalize + vectorized apply (float4 in, uint2 out, +ReLU)
// out row stride ldou2 uint2s, column offset cou2 uint2s
// ---------------------------------------------------------------------------
__global__ __launch_bounds__(512) void pn_finalize(const float* __restrict__ colsum,
                                                   const float* __restrict__ colssq,
                                                   float* __restrict__ mu,
                                                   float* __restrict__ invd) {
  int f = threadIdx.x;
  float m = colsum[f] / (float)NN;
  mu[f] = m;
  float t = colssq[f] / (float)NN - m * m;
  __shared__ float buf[512];
  buf[f] = t;
  __syncthreads();
  for (int off = 256; off > 0; off >>= 1) {
    if (f < off) buf[f] += buf[f + off];
    __syncthreads();
  }
  if (f == 0) invd[0] = 1.0f / (1e-5f + sqrtf(fmaxf(buf[0], 0.0f)));
}

__global__ __launch_bounds__(256) void pn_apply_v(const float* __restrict__ y,
                                                  const float* __restrict__ mu,
                                                  const float* __restrict__ invd,
                                                  unsigned short* __restrict__ xb,
                                                  int ldou2, int cou2) {
  int t = threadIdx.x;
  int r = blockIdx.x * 2 + (t >> 7);
  int f4 = t & 127;
  float id = invd[0];
  float4 v = ((const float4*)(y + (size_t)r * GH_))[f4];
  float4 m = ((const float4*)mu)[f4];
  float v0 = fmaxf((v.x - m.x) * id, 0.0f);
  float v1 = fmaxf((v.y - m.y) * id, 0.0f);
  float v2 = fmaxf((v.z - m.z) * id, 0.0f);
  float v3 = fmaxf((v.w - m.w) * id, 0.0f);
  uint2 o;
  o.x = pack2(v0, v1);
  o.y = pack2(v2, v3);
  ((uint2*)xb)[(size_t)r * ldou2 + cou2 + f4] = o;
}

// ---------------------------------------------------------------------------
extern "C" void kernel_launch(void* const* d_in, const int* in_sizes, int n_in,
                              void* d_out, int out_size, void* d_ws, size_t ws_size,
                              hipStream_t stream) {
  const float* node_features = (const float*)d_in[0];
  const float* node_config   = (const float*)d_in[1];
  const float* emb_table     = (const float*)d_in[2];
  const float* w1  = (const float*)d_in[3];
  const float* b1  = (const float*)d_in[4];
  const float* g1  = (const float*)d_in[5];
  const float* be1 = (const float*)d_in[6];
  const float* w2  = (const float*)d_in[7];
  const float* b2  = (const float*)d_in[8];
  const float* g2  = (const float*)d_in[9];
  const float* be2 = (const float*)d_in[10];
  const float* wl1 = (const float*)d_in[11];
  const float* bl1 = (const float*)d_in[12];
  const float* wr1 = (const float*)d_in[13];
  const float* wl2 = (const float*)d_in[14];
  const float* bl2 = (const float*)d_in[15];
  const float* wr2 = (const float*)d_in[16];
  const float* wl3 = (const float*)d_in[17];
  const float* bl3 = (const float*)d_in[18];
  const float* wr3 = (const float*)d_in[19];
  const float* wc  = (const float*)d_in[20];
  const float* bc  = (const float*)d_in[21];
  const int* node_ops = (const int*)d_in[22];
  const int* edges    = (const int*)d_in[23];
  float* out = (float*)d_out;

  char* ws = (char*)d_ws;
  size_t off = 0;
  auto alloc = [&](size_t bytes) -> void* {
    void* p = ws + off;
    off += (bytes + 255) & ~(size_t)255;
    return p;
  };

  // deg_i + cursor contiguous -> single memset
  int*   deg_i   = (int*)alloc(NN * 4);
  int*   cursor  = (int*)alloc(NN * 4);
  int*   offsets = (int*)alloc((NN + 1) * 4);
  int*   srcs    = (int*)alloc(EE * 4);
  int*   bsum    = (int*)alloc(SS * 4);
  int*   boff    = (int*)alloc(SS * 4);
  float* inv_deg = (float*)alloc(NN * 4);
  float* stat_all= (float*)alloc(2560 * 4);
  float* mu      = (float*)alloc(512 * 4);
  float* invd    = (float*)alloc(256);
  // bf16 weights (padded / packed)
  unsigned short* w1b = (unsigned short*)alloc((size_t)384 * 192 * 2);
  unsigned short* w2b = (unsigned short*)alloc((size_t)256 * 384 * 2);
  unsigned short* wc1 = (unsigned short*)alloc((size_t)512 * 512 * 2);
  unsigned short* wc2 = (unsigned short*)alloc((size_t)512 * 1024 * 2);
  unsigned short* wc3 = (unsigned short*)alloc((size_t)512 * 1024 * 2);
  // activations
  unsigned short* X0  = (unsigned short*)alloc((size_t)NN * 192 * 2);   // 12.6 MB
  unsigned short* H1  = (unsigned short*)alloc((size_t)NN * 384 * 2);   // 25.2 MB
  unsigned short* XC1 = (unsigned short*)alloc((size_t)NN * 512 * 2);   // [agg1|h2] 33.5 MB
  unsigned short* XC2 = (unsigned short*)alloc((size_t)NN * 1024 * 2);  // [agg|x] 67 MB
  float*          Y   = (float*)alloc((size_t)NN * 512 * 4);            // 67 MB

  const int* esrc = edges;
  const int* edst = edges + EE;

  // stat_all regions: gln1 s[0,128) q[128,256) | gln2 s[256,384) q[384,512)
  //                   pn1 cs0[512,1024) cs1[1024,1536) | pn2 cs0[1536,2048) cs1[2048,2560)
  float* gln1s = stat_all;        float* gln1q = stat_all + 128;
  float* gln2s = stat_all + 256;  float* gln2q = stat_all + 384;
  float* pn1s  = stat_all + 512;  float* pn1q  = stat_all + 1024;
  float* pn2s  = stat_all + 1536; float* pn2q  = stat_all + 2048;

  // ---- zero deg + cursor (one memset) ----
  hipMemsetAsync(deg_i, 0, (size_t)NN * 4 * 2, stream);

  // ---- CSR build ----
  deg_count<<<EE / 256, 256, 0, stream>>>(edst, deg_i);
  blk_sum_k<<<NN / 256, 256, 0, stream>>>(deg_i, bsum);
  blk_scan_k<<<1, 128, 0, stream>>>(bsum, boff);
  offsets_k<<<NN / 256, 256, 0, stream>>>(deg_i, boff, offsets, inv_deg);
  bucket_k<<<EE / 256, 256, 0, stream>>>(esrc, edst, offsets, cursor, srcs);

  // ---- prep: stats zero, out init, weights, x0 ----
  prep_all<<<4096, 256, 0, stream>>>(node_features, node_config, emb_table, node_ops,
                                     w1, w2, wl1, wr1, wl2, wr2, wl3, wr3,
                                     w1b, w2b, wc1, wc2, wc3,
                                     X0, stat_all, out, bc);

  // ---- MLP layer 1: Y = leaky(x0@w1^T+b1) + GLN stats; apply -> H1 ----
  {
    dim3 g(3, 256);
    mfma_gemm<<<g, 256, 0, stream>>>(X0, 192, w1b, 192, 192,
                                     b1, Y, 384, DX_, 1, 0,
                                     gln1s, gln1q, nullptr, nullptr);
  }
  gln_apply_bf16<<<NN, 256, 0, stream>>>(Y, 384, DX_, 384, gln1s, gln1q, g1, be1,
                                         H1, 384, 0);

  // ---- MLP layer 2: Y = leaky(h1@w2^T+b2) + GLN stats; apply -> XC1 cols[256,512) ----
  {
    dim3 g(2, 256);
    mfma_gemm<<<g, 256, 0, stream>>>(H1, 384, w2b, 384, 384,
                                     b2, Y, 256, GIN_, 1, 0,
                                     gln2s, gln2q, nullptr, nullptr);
  }
  gln_apply_bf16<<<NN, 256, 0, stream>>>(Y, 256, GIN_, 256, gln2s, gln2q, g2, be2,
                                         XC1, 512, 256);

  // ---- SAGE 1: agg1 -> XC1 cols[0,256); Y = XC1 @ WC1^T (+col stats) ----
  aggregate8<<<NN / 8, 256, 0, stream>>>(XC1, 64, 32, 0, 5, XC1,
                                         offsets, srcs, inv_deg);
  mfma_gemm<<<1024, 256, 0, stream>>>(XC1, 512, wc1, 512, 512,
                                      bl1, Y, 512, GH_, 2, 1,
                                      pn1s, pn1q, nullptr, nullptr);
  pn_finalize<<<1, 512, 0, stream>>>(pn1s, pn1q, mu, invd);
  pn_apply_v<<<NN / 2, 256, 0, stream>>>(Y, mu, invd, XC2, 256, 128);  // x1 -> XC2 cols[512,1024)

  // ---- SAGE 2: agg2 -> XC2 cols[0,512); Y = XC2 @ WC2^T (+col stats) ----
  aggregate8<<<NN / 4, 256, 0, stream>>>(XC2, 128, 64, 0, 6, XC2,
                                         offsets, srcs, inv_deg);
  mfma_gemm<<<1024, 256, 0, stream>>>(XC2, 1024, wc2, 1024, 1024,
                                      bl2, Y, 512, GH_, 2, 1,
                                      pn2s, pn2q, nullptr, nullptr);
  pn_finalize<<<1, 512, 0, stream>>>(pn2s, pn2q, mu, invd);
  pn_apply_v<<<NN / 2, 256, 0, stream>>>(Y, mu, invd, XC2, 256, 128);  // x2 overwrites x1

  // ---- SAGE 3 + head: agg3 -> XC2 cols[0,512); out[seg] += pooled head ----
  aggregate8<<<NN / 4, 256, 0, stream>>>(XC2, 128, 64, 0, 6, XC2,
                                         offsets, srcs, inv_deg);
  mfma_gemm<<<1024, 256, 0, stream>>>(XC2, 1024, wc3, 1024, 1024,
                                      bl3, nullptr, 512, GH_, 3, 1,
                                      nullptr, nullptr, wc, out);
}